// Round 1
// baseline (1315.082 us; speedup 1.0000x reference)
//
#include <hip/hip_runtime.h>

#define BB 16
#define CC 1024
#define HH 32
#define WW 32
#define PP (HH*WW)      // 1024
#define NHEAD 16
#define NTOK (1+PP)     // 1025
#define KK 10
#define TEMP 0.1f
#define MAXENT 96

__device__ __constant__ int c_dy[8] = {-1,-1,-1, 0, 0, 1, 1, 1};
__device__ __constant__ int c_dx[8] = {-1, 0, 1,-1, 1,-1, 0, 1};

// ---------------- K1: ratio = cls_mean / (self_mean + 1e-8), double precision
__global__ void ratio_kernel(const float* __restrict__ attn, double* __restrict__ ratio) {
    int t = blockIdx.x * blockDim.x + threadIdx.x;
    if (t >= BB * PP) return;
    int b = t / PP, p = t % PP;
    size_t baseb = (size_t)b * NHEAD * NTOK * NTOK;
    double sd = 0.0, sc = 0.0;
    for (int h = 0; h < NHEAD; h++) {
        size_t bh = baseb + (size_t)h * NTOK * NTOK;
        sd += (double)attn[bh + (size_t)(p + 1) * NTOK + (p + 1)];
        sc += (double)attn[bh + (p + 1)];
    }
    double self_m = sd / NHEAD, cls_m = sc / NHEAD;
    ratio[t] = cls_m / (self_m + 1e-8);
}

// ---------------- K2: per-batch top-10 argmax (ties -> smaller index)
__global__ void topk_kernel(const double* __restrict__ ratio, int* __restrict__ topk) {
    int b = blockIdx.x;
    __shared__ double sv[PP];
    __shared__ double rv[256];
    __shared__ int    ri[256];
    for (int p = threadIdx.x; p < PP; p += blockDim.x) sv[p] = ratio[b * PP + p];
    __syncthreads();
    for (int k = 0; k < KK; k++) {
        double best = -1e300; int bi = PP;
        for (int p = threadIdx.x; p < PP; p += blockDim.x) {
            double v = sv[p];
            if (v > best || (v == best && p < bi)) { best = v; bi = p; }
        }
        rv[threadIdx.x] = best; ri[threadIdx.x] = bi;
        __syncthreads();
        for (int s = 128; s > 0; s >>= 1) {
            if (threadIdx.x < s) {
                double ov = rv[threadIdx.x + s]; int oi = ri[threadIdx.x + s];
                if (ov > rv[threadIdx.x] || (ov == rv[threadIdx.x] && oi < ri[threadIdx.x])) {
                    rv[threadIdx.x] = ov; ri[threadIdx.x] = oi;
                }
            }
            __syncthreads();
        }
        if (threadIdx.x == 0) { topk[b * KK + k] = ri[0]; sv[ri[0]] = -1e300; }
        __syncthreads();
    }
}

__inline__ __device__ float waveReduceSum(float v) {
    for (int o = 32; o > 0; o >>= 1) v += __shfl_down(v, o, 64);
    return v;
}

// ---------------- K3: cosine sims -> softmax weights + strengths, one block per (b,i)
__global__ void sim_kernel(const float* __restrict__ fm, const int* __restrict__ topk,
                           float* __restrict__ wgt, float* __restrict__ strg) {
    int b = blockIdx.x / KK;
    int i = blockIdx.x % KK;
    int idx = topk[b * KK + i];
    int r = idx / WW, c = idx % WW;
    int npos[8];
    for (int j = 0; j < 8; j++) {
        int y = min(max(r + c_dy[j], 0), HH - 1);
        int x = min(max(c + c_dx[j], 0), WW - 1);
        npos[j] = y * WW + x;
    }
    const float* fb = fm + (size_t)b * CC * PP;
    float no = 0.f, dot[8], nn[8];
    for (int j = 0; j < 8; j++) { dot[j] = 0.f; nn[j] = 0.f; }
    for (int ch = threadIdx.x; ch < CC; ch += blockDim.x) {
        const float* f = fb + (size_t)ch * PP;
        float ov = f[idx];
        no += ov * ov;
        for (int j = 0; j < 8; j++) {
            float nv = f[npos[j]];
            dot[j] += nv * ov;
            nn[j]  += nv * nv;
        }
    }
    __shared__ float red[4][17];
    int lane = threadIdx.x & 63, wv = threadIdx.x >> 6;
    float vals[17];
    vals[0] = no;
    for (int j = 0; j < 8; j++) { vals[1 + j] = dot[j]; vals[9 + j] = nn[j]; }
    for (int t = 0; t < 17; t++) {
        float v = waveReduceSum(vals[t]);
        if (lane == 0) red[wv][t] = v;
    }
    __syncthreads();
    if (threadIdx.x == 0) {
        float tv[17];
        for (int t = 0; t < 17; t++) tv[t] = red[0][t] + red[1][t] + red[2][t] + red[3][t];
        float on = fmaxf(sqrtf(tv[0]), 1e-12f);
        float sim[8], z[8], zmax = -1e30f;
        for (int j = 0; j < 8; j++) {
            float nrm = fmaxf(sqrtf(tv[9 + j]), 1e-12f);
            sim[j] = tv[1 + j] / (on * nrm);
            z[j] = fmaxf(1.f - sim[j], 0.f);
            zmax = fmaxf(zmax, z[j]);
        }
        float se = 0.f, e[8];
        for (int j = 0; j < 8; j++) { e[j] = expf(z[j] - zmax); se += e[j]; }
        for (int j = 0; j < 8; j++) {
            wgt[(b * KK + i) * 8 + j]  = e[j] / se;
            strg[(b * KK + i) * 8 + j] = fminf(fmaxf(sim[j] * TEMP, 0.f), 1.f);
        }
    }
}

// ---------------- K4: resolve last-write-wins -> compact entry list per batch
__global__ void resolve_kernel(const int* __restrict__ topk, int2* __restrict__ entries,
                               int* __restrict__ counts) {
    int b = blockIdx.x;
    __shared__ short mapv[PP];
    for (int p = threadIdx.x; p < PP; p += blockDim.x) mapv[p] = -1;
    __syncthreads();
    if (threadIdx.x == 0) {
        int r[KK], c[KK];
        for (int i = 0; i < KK; i++) {
            int idx = topk[b * KK + i];
            r[i] = idx / WW; c[i] = idx % WW;
        }
        // build winner map in sequential k = i*8+j order
        for (int i = 0; i < KK; i++)
            for (int j = 0; j < 8; j++) {
                int y = min(max(r[i] + c_dy[j], 0), HH - 1);
                int x = min(max(c[i] + c_dx[j], 0), WW - 1);
                if (y != r[i] || x != c[i]) mapv[y * WW + x] = (short)(i * 8 + j);
            }
        // outlier positions always end as wavg -> suppress clean entries there
        for (int i = 0; i < KK; i++) mapv[r[i] * WW + c[i]] = -3;
        int cnt = 0;
        for (int i = 0; i < KK; i++)
            for (int j = 0; j < 8; j++) {
                int y = min(max(r[i] + c_dy[j], 0), HH - 1);
                int x = min(max(c[i] + c_dx[j], 0), WW - 1);
                int pos = y * WW + x;
                if (mapv[pos] == (short)(i * 8 + j)) {
                    entries[b * MAXENT + cnt] = make_int2(pos, i * 8 + j);
                    cnt++;
                }
            }
        for (int i = 0; i < KK; i++) {
            entries[b * MAXENT + cnt] = make_int2(r[i] * WW + c[i], 0x8000 | i);
            cnt++;
        }
        counts[b] = cnt;
    }
}

// ---------------- K5: bulk copy fm -> out
__global__ void copy_kernel(const float4* __restrict__ in, float4* __restrict__ out, int n4) {
    int i = blockIdx.x * blockDim.x + threadIdx.x;
    int stride = gridDim.x * blockDim.x;
    for (; i < n4; i += stride) out[i] = in[i];
}

// ---------------- K6: patch the <=90 special positions per batch
__global__ void patch_kernel(const float* __restrict__ fm, const int* __restrict__ topk,
                             const float* __restrict__ wgt, const float* __restrict__ strg,
                             const int2* __restrict__ entries, const int* __restrict__ counts,
                             float* __restrict__ out) {
    int b = blockIdx.x / MAXENT, e = blockIdx.x % MAXENT;
    if (e >= counts[b]) return;
    int2 en = entries[b * MAXENT + e];
    int pos = en.x, code = en.y;
    const float* fb = fm + (size_t)b * CC * PP;
    float* ob = out + (size_t)b * CC * PP;
    if (code & 0x8000) {
        int i = code & 0xF;
        int idx = topk[b * KK + i];
        int r = idx / WW, c = idx % WW;
        int npos[8]; float w[8];
        for (int j = 0; j < 8; j++) {
            int y = min(max(r + c_dy[j], 0), HH - 1);
            int x = min(max(c + c_dx[j], 0), WW - 1);
            npos[j] = y * WW + x;
            w[j] = wgt[(b * KK + i) * 8 + j];
        }
        for (int ch = threadIdx.x; ch < CC; ch += blockDim.x) {
            const float* f = fb + (size_t)ch * PP;
            float acc = 0.f;
            for (int j = 0; j < 8; j++) acc += f[npos[j]] * w[j];
            ob[(size_t)ch * PP + pos] = acc;
        }
    } else {
        int i = code >> 3;
        int cpos = topk[b * KK + i];
        float s = strg[(b * KK + i) * 8 + (code & 7)];
        for (int ch = threadIdx.x; ch < CC; ch += blockDim.x) {
            const float* f = fb + (size_t)ch * PP;
            ob[(size_t)ch * PP + pos] = f[pos] - f[cpos] * s;
        }
    }
}

extern "C" void kernel_launch(void* const* d_in, const int* in_sizes, int n_in,
                              void* d_out, int out_size, void* d_ws, size_t ws_size,
                              hipStream_t stream) {
    const float* fm   = (const float*)d_in[0];
    const float* attn = (const float*)d_in[1];
    float* out = (float*)d_out;

    char* ws = (char*)d_ws;
    double* ratio  = (double*)(ws + 0);                       // 16384 * 8 = 131072
    int*    topk   = (int*)   (ws + 131072);                  // 160 * 4
    float*  wgt    = (float*) (ws + 132096);                  // 1280 * 4
    float*  strg   = (float*) (ws + 137216);                  // 1280 * 4
    int2*   entries= (int2*)  (ws + 142336);                  // 16*96 * 8
    int*    counts = (int*)   (ws + 154624);                  // 16 * 4

    ratio_kernel<<<(BB * PP + 255) / 256, 256, 0, stream>>>(attn, ratio);
    topk_kernel<<<BB, 256, 0, stream>>>(ratio, topk);
    sim_kernel<<<BB * KK, 256, 0, stream>>>(fm, topk, wgt, strg);
    resolve_kernel<<<BB, 64, 0, stream>>>(topk, entries, counts);
    int n4 = BB * CC * PP / 4;
    copy_kernel<<<1024, 256, 0, stream>>>((const float4*)fm, (float4*)out, n4);
    patch_kernel<<<BB * MAXENT, 256, 0, stream>>>(fm, topk, wgt, strg, entries, counts, out);
}